// Round 4
// baseline (421.724 us; speedup 1.0000x reference)
//
#include <hip/hip_runtime.h>
#include <hip/hip_bf16.h>

// B=256, IN=512, OUT=512
//   y_mean = x_mean @ A_mean + b_mean
//   y_var  = diag_embed( (diag(x_var)+x_mean^2) @ A_var + diag(A^T Cov A) + b_var )
// term2[b,o] = sum_i A[i,o] * (x_var[b] @ A)[i,o]  -> stacked GEMM + weighted colsum
//
// k_gemm2 stages x_var f32 DIRECTLY with global_load_lds using pre-swizzled
// per-lane source addresses (linear LDS dest, XOR-involution on 16B chunks
// within 128B rows), converts f32->bf16 at fragment load (compiler emits
// v_cvt_pk_bf16_f32). It also zero-fills its stripe of y_var; k_diagw then
// writes the diagonal.

typedef __bf16 bf16x8 __attribute__((ext_vector_type(8)));
typedef float f32x4 __attribute__((ext_vector_type(4)));

__device__ inline ushort f2bf(float f) {
    union { float f; unsigned u; } x; x.f = f;
    unsigned u = x.u + 0x7fffu + ((x.u >> 16) & 1u);   // RNE
    return (ushort)(u >> 16);
}

__device__ inline void gload16(const void* g, void* l) {
    __builtin_amdgcn_global_load_lds(
        (const __attribute__((address_space(1))) void*)g,
        (__attribute__((address_space(3))) void*)l, 16, 0, 0);
}

// ---- kernel 1: A_mean -> bf16 A^T tile images: abt[(nt*8+ks)*16KB] ----
// image byte = r*128 + ((c ^ (r&7))*16) + e*2 ; value = A[ks*64+c*8+e][nt*128+r]
__global__ void k_prep_at(const float* __restrict__ am, ushort* __restrict__ abt) {
    int C = blockIdx.x * 256 + threadIdx.x;   // chunk id 0..32767
    int nt = C >> 13;
    int L  = C & 8191;
    int ks = L >> 10;
    int rem = L & 1023;
    int r = rem >> 3, cs = rem & 7;
    int c = cs ^ (r & 7);
    int o = nt * 128 + r;
    int j0 = ks * 64 + c * 8;
    ushort u[8];
    #pragma unroll
    for (int e = 0; e < 8; ++e) u[e] = f2bf(am[(j0 + e) * 512 + o]);
    *(int4*)(abt + (long)C * 8) = *(int4*)u;
}

// ---- kernel 2: y_mean and pd = term1 + b_var (diag extraction fused) ----
__global__ void k_mean_t1(const float* __restrict__ xv, const float* __restrict__ xm,
                          const float* __restrict__ am, const float* __restrict__ av,
                          const float* __restrict__ bm, const float* __restrict__ bv,
                          float* __restrict__ ymean, float* __restrict__ pd) {
    __shared__ float xmS[512];
    __shared__ float xxS[512];
    int t = threadIdx.x;
    int b  = blockIdx.x >> 1;
    int o0 = (blockIdx.x & 1) * 256;
    #pragma unroll
    for (int q = 0; q < 2; ++q) {
        int i = q * 256 + t;
        float m = xm[b * 512 + i];
        xmS[i] = m;
        xxS[i] = xv[(long)b * 262144 + i * 513] + m * m;   // x_var[b,i,i] + m^2
    }
    __syncthreads();
    int o = o0 + t;
    float ym = bm[o], t1 = bv[o];
    #pragma unroll 8
    for (int i = 0; i < 512; ++i) {
        ym = fmaf(xmS[i], am[i * 512 + o], ym);
        t1 = fmaf(xxS[i], av[i * 512 + o], t1);
    }
    ymean[b * 512 + o] = ym;
    pd[b * 512 + o]    = t1;
}

// ---- kernel 3: MFMA GEMM, f32 X direct-staged + A images; zero-fills y_var ----
__global__ __launch_bounds__(256, 2) void k_gemm2(
        const float*  __restrict__ xv,    // Xflat [131072][512] f32
        const ushort* __restrict__ abt,   // A^T tile images [4][8][16KB]
        const float*  __restrict__ amean, // A f32 [j][o]
        float* __restrict__ p2,           // [256][4][512]
        float* __restrict__ yvar)         // [256][512][512]
{
    __shared__ float  ldsX[2][4096];      // 16KB: 128 rows x 32 f32 (swizzled chunks)
    __shared__ ushort ldsA[2][8192];      // 16KB: 128 rows x 64 bf16 (swizzled chunks)
    __shared__ float  red[2][128];

    int t = threadIdx.x;
    int lane = t & 63;
    int wave = t >> 6;
    int wm = wave >> 1, wn = wave & 1;

    int bid = blockIdx.x;
    int swz = (bid & 7) * 512 + (bid >> 3);   // bijective XCD swizzle (4096%8==0)
    int mtile = swz >> 2;                     // 0..1023
    int ntile = swz & 3;
    int n0 = ntile * 128;
    long m0 = (long)mtile * 128;

    f32x4 acc[4][4];
    #pragma unroll
    for (int a = 0; a < 4; ++a)
        #pragma unroll
        for (int bq = 0; bq < 4; ++bq)
            acc[a][bq] = (f32x4){0.f, 0.f, 0.f, 0.f};

    // X staging: chunk L=q*256+t -> LDS byte L*16; row r=q*32+(t>>3),
    // phys chunk cs=t&7 holds logical chunk cs^(r&7) -> source col pre-XORed.
    int rb = t >> 3;
    int ps = (t & 7) ^ (rb & 7);
    const float* xsrc = xv + (m0 + rb) * 512 + ps * 4;
    const char*  asrc = (const char*)abt + (long)ntile * 131072 + t * 16;

    auto stageX = [&](int buf, int ks) {
        char* xd = (char*)ldsX[buf] + wave * 1024;
        const float* s = xsrc + ks * 32;
        #pragma unroll
        for (int q = 0; q < 4; ++q)
            gload16(s + q * 32 * 512, xd + q * 4096);
    };
    auto stageA = [&](int buf, int ka) {
        char* ad = (char*)ldsA[buf] + wave * 1024;
        const char* s = asrc + (long)ka * 16384;
        #pragma unroll
        for (int q = 0; q < 4; ++q)
            gload16(s + q * 4096, ad + q * 4096);
    };

    auto compute = [&](int xb, int ab, int kc) {
        bf16x8 af[4], bfr[4];
        int kb = kc * 64 + (lane >> 4) * 16;
        int c0 = (lane >> 4) * 2;
        #pragma unroll
        for (int mf = 0; mf < 4; ++mf) {
            int r = wm * 64 + mf * 16 + (lane & 15);
            int sw = r & 7;
            const char* base = (const char*)ldsX[xb] + r * 128;
            f32x4 lo = *(const f32x4*)(base + ((c0 ^ sw) << 4));
            f32x4 hi = *(const f32x4*)(base + (((c0 + 1) ^ sw) << 4));
            bf16x8 a;
            a[0] = (__bf16)lo[0]; a[1] = (__bf16)lo[1];
            a[2] = (__bf16)lo[2]; a[3] = (__bf16)lo[3];
            a[4] = (__bf16)hi[0]; a[5] = (__bf16)hi[1];
            a[6] = (__bf16)hi[2]; a[7] = (__bf16)hi[3];
            af[mf] = a;
        }
        #pragma unroll
        for (int nf = 0; nf < 4; ++nf) {
            int r = wn * 64 + nf * 16 + (lane & 15);
            bfr[nf] = *(const bf16x8*)((const char*)ldsA[ab] + r * 128
                                       + (kb ^ ((r & 7) << 4)));
        }
        #pragma unroll
        for (int mf = 0; mf < 4; ++mf)
            #pragma unroll
            for (int nf = 0; nf < 4; ++nf)
                acc[mf][nf] = __builtin_amdgcn_mfma_f32_16x16x32_bf16(
                    af[mf], bfr[nf], acc[mf][nf], 0, 0, 0);
    };

    stageX(0, 0); stageA(0, 0);
    __syncthreads();
    int xb = 0, ab = 0;
    for (int ks = 0; ks < 16; ++ks) {
        if (ks < 15) stageX(xb ^ 1, ks + 1);
        if (!(ks & 1) && ks < 14) stageA(ab ^ 1, (ks >> 1) + 1);
        compute(xb, ab, ks & 1);
        __syncthreads();
        xb ^= 1;
        ab ^= (ks & 1);
    }

    // epilogue A: weighted colsum  term2_partial[o] = sum_rows A[i,o]*C[i,o]
    int msub = mtile & 3;
    int b = mtile >> 2;
    #pragma unroll
    for (int nf = 0; nf < 4; ++nf) {
        float p = 0.f;
        int o = n0 + wn * 64 + nf * 16 + (lane & 15);
        #pragma unroll
        for (int mf = 0; mf < 4; ++mf) {
            #pragma unroll
            for (int j = 0; j < 4; ++j) {
                int i = msub * 128 + wm * 64 + mf * 16 + ((lane >> 4) * 4) + j;
                p += acc[mf][nf][j] * amean[i * 512 + o];
            }
        }
        p += __shfl_xor(p, 16, 64);
        p += __shfl_xor(p, 32, 64);
        if (lane < 16) red[wm][wn * 64 + nf * 16 + lane] = p;
    }
    __syncthreads();
    if (t < 128) {
        float v = red[0][t] + red[1][t];
        p2[((long)b * 4 + msub) * 512 + n0 + t] = v;
    }

    // epilogue B: zero-fill this block's disjoint 32-row stripe of y_var[b]
    // (diagonal written afterwards by k_diagw)
    float4 z = make_float4(0.f, 0.f, 0.f, 0.f);
    float* zbase = yvar + ((long)b * 512 + msub * 128 + ntile * 32) * 512;
    #pragma unroll
    for (int q = 0; q < 16; ++q) {
        int F = q * 256 + t;                 // 0..4095 float4s = 32 rows x 512 f32
        *(float4*)(zbase + (long)F * 4) = z;
    }
}

// ---- kernel 4: write y_var diagonal = pd + sum(p2 partials) ----
__global__ void k_diagw(const float* __restrict__ pd, const float* __restrict__ p2,
                        float* __restrict__ yvar) {
    int idx = blockIdx.x * 256 + threadIdx.x;    // 0..131071 (b*512+o)
    int b = idx >> 9, o = idx & 511;
    long pb = (long)b * 2048 + o;
    float v = pd[idx] + p2[pb] + p2[pb + 512] + p2[pb + 1024] + p2[pb + 1536];
    yvar[(long)idx * 512 + o] = v;
}

extern "C" void kernel_launch(void* const* d_in, const int* in_sizes, int n_in,
                              void* d_out, int out_size, void* d_ws, size_t ws_size,
                              hipStream_t stream) {
    const float* x_mean = (const float*)d_in[0];
    const float* x_var  = (const float*)d_in[1];
    const float* A_mean = (const float*)d_in[2];
    const float* A_var  = (const float*)d_in[3];
    const float* b_mean = (const float*)d_in[4];
    const float* b_var  = (const float*)d_in[5];

    float* ymean = (float*)d_out;                  // [256,512]
    float* yvar  = (float*)d_out + 131072;         // [256,512,512]

    char* ws = (char*)d_ws;
    ushort* abt = (ushort*)ws;                     // 512 KB (A^T tile images)
    float*  pd  = (float*)(ws + 512 * 1024);       // [256,512]
    float*  p2  = (float*)(ws + 1024 * 1024);      // [256,4,512]

    k_prep_at<<<128, 256, 0, stream>>>(A_mean, abt);
    k_mean_t1<<<512, 256, 0, stream>>>(x_var, x_mean, A_mean, A_var, b_mean, b_var,
                                       ymean, pd);
    k_gemm2<<<4096, 256, 0, stream>>>(x_var, abt, A_mean, p2, yvar);
    k_diagw<<<512, 256, 0, stream>>>(pd, p2, yvar);
}

// Round 5
// 370.844 us; speedup vs baseline: 1.1372x; 1.1372x over previous
//
#include <hip/hip_runtime.h>
#include <hip/hip_bf16.h>

// B=256, IN=512, OUT=512
//   y_mean = x_mean @ A_mean + b_mean
//   y_var  = diag_embed( (diag(x_var)+x_mean^2) @ A_var + diag(A^T Cov A) + b_var )
// term2[b,o] = sum_i A[i,o] * (x_var[b] @ A)[i,o]  -> stacked GEMM + weighted colsum
//
// k_gemm2: m97-style single-buffer 2-barrier loop, BK=64, 8 steps, 3 blocks/CU.
// X staged as f32 via global_load_lds with pre-XOR-swizzled per-lane sources
// (linear LDS dest); f32->bf16 at fragment load. Zero-fill of y_var interleaved
// into the K-loop; k_diagw writes the diagonal afterwards.

typedef __bf16 bf16x8 __attribute__((ext_vector_type(8)));
typedef float f32x4 __attribute__((ext_vector_type(4)));

__device__ inline ushort f2bf(float f) {
    union { float f; unsigned u; } x; x.f = f;
    unsigned u = x.u + 0x7fffu + ((x.u >> 16) & 1u);   // RNE
    return (ushort)(u >> 16);
}

__device__ inline void gload16(const void* g, void* l) {
    __builtin_amdgcn_global_load_lds(
        (const __attribute__((address_space(1))) void*)g,
        (__attribute__((address_space(3))) void*)l, 16, 0, 0);
}

// ---- kernel 1: A_mean -> bf16 A^T tile images: abt[(nt*8+ks)*16KB] ----
// image byte = r*128 + ((c ^ (r&7))*16) + e*2 ; value = A[ks*64+c*8+e][nt*128+r]
__global__ void k_prep_at(const float* __restrict__ am, ushort* __restrict__ abt) {
    int C = blockIdx.x * 256 + threadIdx.x;   // chunk id 0..32767
    int nt = C >> 13;
    int L  = C & 8191;
    int ks = L >> 10;
    int rem = L & 1023;
    int r = rem >> 3, cs = rem & 7;
    int c = cs ^ (r & 7);
    int o = nt * 128 + r;
    int j0 = ks * 64 + c * 8;
    ushort u[8];
    #pragma unroll
    for (int e = 0; e < 8; ++e) u[e] = f2bf(am[(j0 + e) * 512 + o]);
    *(int4*)(abt + (long)C * 8) = *(int4*)u;
}

// ---- kernel 2: y_mean and pd = term1 + b_var (diag extraction fused) ----
__global__ void k_mean_t1(const float* __restrict__ xv, const float* __restrict__ xm,
                          const float* __restrict__ am, const float* __restrict__ av,
                          const float* __restrict__ bm, const float* __restrict__ bv,
                          float* __restrict__ ymean, float* __restrict__ pd) {
    __shared__ float xmS[512];
    __shared__ float xxS[512];
    int t = threadIdx.x;
    int b  = blockIdx.x >> 1;
    int o0 = (blockIdx.x & 1) * 256;
    #pragma unroll
    for (int q = 0; q < 2; ++q) {
        int i = q * 256 + t;
        float m = xm[b * 512 + i];
        xmS[i] = m;
        xxS[i] = xv[(long)b * 262144 + i * 513] + m * m;   // x_var[b,i,i] + m^2
    }
    __syncthreads();
    int o = o0 + t;
    float ym = bm[o], t1 = bv[o];
    #pragma unroll 8
    for (int i = 0; i < 512; ++i) {
        ym = fmaf(xmS[i], am[i * 512 + o], ym);
        t1 = fmaf(xxS[i], av[i * 512 + o], t1);
    }
    ymean[b * 512 + o] = ym;
    pd[b * 512 + o]    = t1;
}

// ---- kernel 3: MFMA GEMM, single-buffer 2-barrier, fused zero-fill ----
__global__ __launch_bounds__(256, 3) void k_gemm2(
        const float*  __restrict__ xv,    // Xflat [131072][512] f32
        const ushort* __restrict__ abt,   // A^T tile images [4][8][16KB]
        const float*  __restrict__ amean, // A f32 [j][o]
        float* __restrict__ p2,           // [256][4][512]
        float* __restrict__ yvar)         // [256][512][512]
{
    __shared__ float  ldsX[8192];         // 32KB: 128 rows x 64 f32, 16 chunks/row
    __shared__ ushort ldsA[8192];         // 16KB: 128 rows x 64 bf16, 8 chunks/row
    __shared__ float  red[2][128];

    int t = threadIdx.x;
    int lane = t & 63;
    int wave = t >> 6;
    int wm = wave >> 1, wn = wave & 1;

    int bid = blockIdx.x;
    int swz = (bid & 7) * 512 + (bid >> 3);   // bijective XCD swizzle (4096%8==0)
    int mtile = swz >> 2;                     // 0..1023
    int ntile = swz & 3;
    int n0 = ntile * 128;
    long m0 = (long)mtile * 128;
    int msub = mtile & 3;
    int b = mtile >> 2;

    f32x4 acc[4][4];
    #pragma unroll
    for (int a = 0; a < 4; ++a)
        #pragma unroll
        for (int bq = 0; bq < 4; ++bq)
            acc[a][bq] = (f32x4){0.f, 0.f, 0.f, 0.f};

    // X stage: instr q, lane l -> LDS byte wave*8192 + q*1024 + l*16
    //   row = wave*32 + q*4 + (l>>4), phys chunk cs = l&15 holds logical cs^(row&7)
    int rl = lane >> 4;
    int cle = (lane & 15) ^ rl;
    const float* xb_e = xv + (m0 + wave * 32 + rl) * 512 + cle * 4;          // even q
    const float* xb_o = xv + (m0 + wave * 32 + 4 + rl) * 512 + (cle ^ 4) * 4; // odd q

    auto stageX = [&](int ks) {
        char* xd = (char*)ldsX + wave * 8192;
        #pragma unroll
        for (int q = 0; q < 8; q += 2) {
            gload16(xb_e + ks * 64 + q * 4 * 512, xd + q * 1024);
            gload16(xb_o + ks * 64 + q * 4 * 512, xd + (q + 1) * 1024);
        }
    };
    const char* asrc = (const char*)abt + (long)ntile * 131072
                       + wave * 4096 + (lane << 4);
    auto stageA = [&](int ks) {
        char* ad = (char*)ldsA + wave * 4096;
        const char* s = asrc + ks * 16384;
        #pragma unroll
        for (int q = 0; q < 4; ++q)
            gload16(s + q * 1024, ad + q * 1024);
    };

    float* zb = yvar + ((long)b * 512 + msub * 128 + ntile * 32) * 512 + t * 4;

    auto compute = [&](int kc) {
        bf16x8 af[4], bfr[4];
        int g = lane >> 4;
        int kb = kc * 64 + g * 16;
        #pragma unroll
        for (int nf = 0; nf < 4; ++nf) {
            int r = wn * 64 + nf * 16 + (lane & 15);
            bfr[nf] = *(const bf16x8*)((const char*)ldsA + r * 128
                                       + (kb ^ ((r & 7) << 4)));
        }
        #pragma unroll
        for (int mf = 0; mf < 4; ++mf) {
            int r = wm * 64 + mf * 16 + (lane & 15);
            int sw = r & 7;
            const char* bx = (const char*)ldsX + r * 256 + kc * 128;
            f32x4 lo = *(const f32x4*)(bx + (((2 * g) ^ sw) << 4));
            f32x4 hi = *(const f32x4*)(bx + (((2 * g + 1) ^ sw) << 4));
            bf16x8 a;
            a[0] = (__bf16)lo[0]; a[1] = (__bf16)lo[1];
            a[2] = (__bf16)lo[2]; a[3] = (__bf16)lo[3];
            a[4] = (__bf16)hi[0]; a[5] = (__bf16)hi[1];
            a[6] = (__bf16)hi[2]; a[7] = (__bf16)hi[3];
            af[mf] = a;
        }
        #pragma unroll
        for (int mf = 0; mf < 4; ++mf)
            #pragma unroll
            for (int nf = 0; nf < 4; ++nf)
                acc[mf][nf] = __builtin_amdgcn_mfma_f32_16x16x32_bf16(
                    af[mf], bfr[nf], acc[mf][nf], 0, 0, 0);
    };

    for (int ks = 0; ks < 8; ++ks) {
        stageX(ks);
        stageA(ks);
        {   // interleaved zero-fill: 2 float4 per thread per step (64KB/block total)
            float4 z = make_float4(0.f, 0.f, 0.f, 0.f);
            *(float4*)(zb + ks * 2048) = z;
            *(float4*)(zb + ks * 2048 + 1024) = z;
        }
        __syncthreads();      // compiler drains vmcnt -> LDS ready
        compute(0);
        compute(1);
        __syncthreads();      // reads done before next stage overwrites
    }

    // epilogue: weighted colsum  term2_partial[o] = sum_rows A[i,o]*C[i,o]
    #pragma unroll
    for (int nf = 0; nf < 4; ++nf) {
        float p = 0.f;
        int o = n0 + wn * 64 + nf * 16 + (lane & 15);
        #pragma unroll
        for (int mf = 0; mf < 4; ++mf) {
            #pragma unroll
            for (int j = 0; j < 4; ++j) {
                int i = msub * 128 + wm * 64 + mf * 16 + ((lane >> 4) * 4) + j;
                p += acc[mf][nf][j] * amean[i * 512 + o];
            }
        }
        p += __shfl_xor(p, 16, 64);
        p += __shfl_xor(p, 32, 64);
        if (lane < 16) red[wm][wn * 64 + nf * 16 + lane] = p;
    }
    __syncthreads();
    if (t < 128) {
        float v = red[0][t] + red[1][t];
        p2[((long)b * 4 + msub) * 512 + n0 + t] = v;
    }
}

// ---- kernel 4: write y_var diagonal = pd + sum(p2 partials) ----
__global__ void k_diagw(const float* __restrict__ pd, const float* __restrict__ p2,
                        float* __restrict__ yvar) {
    int idx = blockIdx.x * 256 + threadIdx.x;    // 0..131071 (b*512+o)
    int b = idx >> 9, o = idx & 511;
    long pb = (long)b * 2048 + o;
    float v = pd[idx] + p2[pb] + p2[pb + 512] + p2[pb + 1024] + p2[pb + 1536];
    yvar[(long)idx * 512 + o] = v;
}

extern "C" void kernel_launch(void* const* d_in, const int* in_sizes, int n_in,
                              void* d_out, int out_size, void* d_ws, size_t ws_size,
                              hipStream_t stream) {
    const float* x_mean = (const float*)d_in[0];
    const float* x_var  = (const float*)d_in[1];
    const float* A_mean = (const float*)d_in[2];
    const float* A_var  = (const float*)d_in[3];
    const float* b_mean = (const float*)d_in[4];
    const float* b_var  = (const float*)d_in[5];

    float* ymean = (float*)d_out;                  // [256,512]
    float* yvar  = (float*)d_out + 131072;         // [256,512,512]

    char* ws = (char*)d_ws;
    ushort* abt = (ushort*)ws;                     // 512 KB (A^T tile images)
    float*  pd  = (float*)(ws + 512 * 1024);       // [256,512]
    float*  p2  = (float*)(ws + 1024 * 1024);      // [256,4,512]

    k_prep_at<<<128, 256, 0, stream>>>(A_mean, abt);
    k_mean_t1<<<512, 256, 0, stream>>>(x_var, x_mean, A_mean, A_var, b_mean, b_var,
                                       ymean, pd);
    k_gemm2<<<4096, 256, 0, stream>>>(x_var, abt, A_mean, p2, yvar);
    k_diagw<<<512, 256, 0, stream>>>(pd, p2, yvar);
}

// Round 6
// 202.865 us; speedup vs baseline: 2.0788x; 1.8280x over previous
//
#include <hip/hip_runtime.h>
#include <hip/hip_bf16.h>

// B=256, IN=512, OUT=512
//   y_mean = x_mean @ A_mean + b_mean
//   y_var  = diag_embed( (diag(x_var)+x_mean^2) @ A_var + diag(A^T Cov A) + b_var )
// term2[b,o] = sum_i A[i,o] * (x_var[b] @ A)[i,o]  -> stacked GEMM + weighted colsum
//
// k_gemm2: m97-style single-buffer 2-barrier loop, BK=64, 8 steps, 3 blocks/CU,
// X staged f32 via global_load_lds w/ pre-XOR-swizzled sources; f32->bf16 at
// fragment load; zero-fill of y_var issued after the K-loop (no in-loop drains).
// Small GEMMs (y_mean, term1) done TLP-style: k_diag -> k_t1 (partials) -> k_final.

typedef __bf16 bf16x8 __attribute__((ext_vector_type(8)));
typedef float f32x4 __attribute__((ext_vector_type(4)));

__device__ inline ushort f2bf(float f) {
    union { float f; unsigned u; } x; x.f = f;
    unsigned u = x.u + 0x7fffu + ((x.u >> 16) & 1u);   // RNE
    return (ushort)(u >> 16);
}

__device__ inline void gload16(const void* g, void* l) {
    __builtin_amdgcn_global_load_lds(
        (const __attribute__((address_space(1))) void*)g,
        (__attribute__((address_space(3))) void*)l, 16, 0, 0);
}

// ---- kernel 1: A_mean -> bf16 A^T tile images: abt[(nt*8+ks)*16KB] ----
// image byte = r*128 + ((c ^ (r&7))*16) + e*2 ; value = A[ks*64+c*8+e][nt*128+r]
__global__ void k_prep_at(const float* __restrict__ am, ushort* __restrict__ abt) {
    int C = blockIdx.x * 256 + threadIdx.x;   // chunk id 0..32767
    int nt = C >> 13;
    int L  = C & 8191;
    int ks = L >> 10;
    int rem = L & 1023;
    int r = rem >> 3, cs = rem & 7;
    int c = cs ^ (r & 7);
    int o = nt * 128 + r;
    int j0 = ks * 64 + c * 8;
    ushort u[8];
    #pragma unroll
    for (int e = 0; e < 8; ++e) u[e] = f2bf(am[(j0 + e) * 512 + o]);
    *(int4*)(abt + (long)C * 8) = *(int4*)u;
}

// ---- kernel 2: xx[b][i] = x_var[b,i,i] + x_mean^2 ----
__global__ void k_diag(const float* __restrict__ xv, const float* __restrict__ xm,
                       float* __restrict__ xx) {
    int idx = blockIdx.x * 256 + threadIdx.x;     // b*512+i
    int b = idx >> 9, i = idx & 511;
    float m = xm[idx];
    xx[idx] = xv[(long)b * 262144 + i * 513] + m * m;
}

// ---- kernel 3: partial small GEMMs: yp/tp[ic][b][o] over 64-i chunks ----
__global__ void k_t1(const float* __restrict__ xm, const float* __restrict__ xx,
                     const float* __restrict__ am, const float* __restrict__ av,
                     float* __restrict__ yp, float* __restrict__ tp) {
    __shared__ float S[2][64];
    int t = threadIdx.x;
    int b  = blockIdx.x >> 3;
    int ic = blockIdx.x & 7;
    int i0 = ic * 64;
    if (t < 128) {
        int which = t >> 6, ii = t & 63;
        const float* src = which ? xx : xm;
        S[which][ii] = src[b * 512 + i0 + ii];
    }
    __syncthreads();
    int mat = t >> 7;                 // wave-uniform: 0 -> am/ym, 1 -> av/t1
    int o4 = t & 127;
    const float* M = mat ? av : am;
    const float* Sv = S[mat];
    f32x4 acc = {0.f, 0.f, 0.f, 0.f};
    #pragma unroll 8
    for (int ii = 0; ii < 64; ++ii) {
        f32x4 a = *(const f32x4*)(M + (long)(i0 + ii) * 512 + o4 * 4);
        float s = Sv[ii];
        acc[0] = fmaf(s, a[0], acc[0]);
        acc[1] = fmaf(s, a[1], acc[1]);
        acc[2] = fmaf(s, a[2], acc[2]);
        acc[3] = fmaf(s, a[3], acc[3]);
    }
    float* dst = (mat ? tp : yp) + ((long)ic * 256 + b) * 512 + o4 * 4;
    *(f32x4*)dst = acc;
}

// ---- kernel 4: MFMA GEMM, single-buffer 2-barrier, post-loop zero-fill ----
__global__ __launch_bounds__(256, 3) void k_gemm2(
        const float*  __restrict__ xv,    // Xflat [131072][512] f32
        const ushort* __restrict__ abt,   // A^T tile images [4][8][16KB]
        const float*  __restrict__ amean, // A f32 [j][o]
        float* __restrict__ p2,           // [256][4][512]
        float* __restrict__ yvar)         // [256][512][512]
{
    __shared__ float  ldsX[8192];         // 32KB: 128 rows x 64 f32, 16 chunks/row
    __shared__ ushort ldsA[8192];         // 16KB: 128 rows x 64 bf16, 8 chunks/row
    __shared__ float  red[2][128];

    int t = threadIdx.x;
    int lane = t & 63;
    int wave = t >> 6;
    int wm = wave >> 1, wn = wave & 1;

    int bid = blockIdx.x;
    int swz = (bid & 7) * 512 + (bid >> 3);   // bijective XCD swizzle (4096%8==0)
    int mtile = swz >> 2;                     // 0..1023
    int ntile = swz & 3;
    int n0 = ntile * 128;
    long m0 = (long)mtile * 128;
    int msub = mtile & 3;
    int b = mtile >> 2;

    f32x4 acc[4][4];
    #pragma unroll
    for (int a = 0; a < 4; ++a)
        #pragma unroll
        for (int bq = 0; bq < 4; ++bq)
            acc[a][bq] = (f32x4){0.f, 0.f, 0.f, 0.f};

    // X stage: instr q, lane l -> LDS byte wave*8192 + q*1024 + l*16
    //   row = wave*32 + q*4 + (l>>4), phys chunk cs = l&15 holds logical cs^(row&7)
    int rl = lane >> 4;
    int cle = (lane & 15) ^ rl;
    const float* xb_e = xv + (m0 + wave * 32 + rl) * 512 + cle * 4;          // even q
    const float* xb_o = xv + (m0 + wave * 32 + 4 + rl) * 512 + (cle ^ 4) * 4; // odd q

    auto stageX = [&](int ks) {
        char* xd = (char*)ldsX + wave * 8192;
        #pragma unroll
        for (int q = 0; q < 8; q += 2) {
            gload16(xb_e + ks * 64 + q * 4 * 512, xd + q * 1024);
            gload16(xb_o + ks * 64 + q * 4 * 512, xd + (q + 1) * 1024);
        }
    };
    const char* asrc = (const char*)abt + (long)ntile * 131072
                       + wave * 4096 + (lane << 4);
    auto stageA = [&](int ks) {
        char* ad = (char*)ldsA + wave * 4096;
        const char* s = asrc + ks * 16384;
        #pragma unroll
        for (int q = 0; q < 4; ++q)
            gload16(s + q * 1024, ad + q * 1024);
    };

    float* zb = yvar + ((long)b * 512 + msub * 128 + ntile * 32) * 512 + t * 4;

    auto compute = [&](int kc) {
        bf16x8 af[4], bfr[4];
        int g = lane >> 4;
        int kb = kc * 64 + g * 16;
        #pragma unroll
        for (int nf = 0; nf < 4; ++nf) {
            int r = wn * 64 + nf * 16 + (lane & 15);
            bfr[nf] = *(const bf16x8*)((const char*)ldsA + r * 128
                                       + (kb ^ ((r & 7) << 4)));
        }
        #pragma unroll
        for (int mf = 0; mf < 4; ++mf) {
            int r = wm * 64 + mf * 16 + (lane & 15);
            int sw = r & 7;
            const char* bx = (const char*)ldsX + r * 256 + kc * 128;
            f32x4 lo = *(const f32x4*)(bx + (((2 * g) ^ sw) << 4));
            f32x4 hi = *(const f32x4*)(bx + (((2 * g + 1) ^ sw) << 4));
            bf16x8 a;
            a[0] = (__bf16)lo[0]; a[1] = (__bf16)lo[1];
            a[2] = (__bf16)lo[2]; a[3] = (__bf16)lo[3];
            a[4] = (__bf16)hi[0]; a[5] = (__bf16)hi[1];
            a[6] = (__bf16)hi[2]; a[7] = (__bf16)hi[3];
            af[mf] = a;
        }
        #pragma unroll
        for (int mf = 0; mf < 4; ++mf)
            #pragma unroll
            for (int nf = 0; nf < 4; ++nf)
                acc[mf][nf] = __builtin_amdgcn_mfma_f32_16x16x32_bf16(
                    af[mf], bfr[nf], acc[mf][nf], 0, 0, 0);
    };

    for (int ks = 0; ks < 8; ++ks) {
        stageX(ks);
        stageA(ks);
        __syncthreads();      // drain vmcnt -> LDS ready
        compute(0);
        compute(1);
        __syncthreads();      // reads done before next stage overwrites
    }

    // zero-fill this block's disjoint 32-row stripe of y_var[b] (diag written later)
    {
        float4 z = make_float4(0.f, 0.f, 0.f, 0.f);
        #pragma unroll
        for (int q = 0; q < 16; ++q)
            *(float4*)(zb + (long)q * 1024) = z;
    }

    // epilogue: weighted colsum  term2_partial[o] = sum_rows A[i,o]*C[i,o]
    #pragma unroll
    for (int nf = 0; nf < 4; ++nf) {
        float p = 0.f;
        int o = n0 + wn * 64 + nf * 16 + (lane & 15);
        #pragma unroll
        for (int mf = 0; mf < 4; ++mf) {
            #pragma unroll
            for (int j = 0; j < 4; ++j) {
                int i = msub * 128 + wm * 64 + mf * 16 + ((lane >> 4) * 4) + j;
                p += acc[mf][nf][j] * amean[i * 512 + o];
            }
        }
        p += __shfl_xor(p, 16, 64);
        p += __shfl_xor(p, 32, 64);
        if (lane < 16) red[wm][wn * 64 + nf * 16 + lane] = p;
    }
    __syncthreads();
    if (t < 128) {
        float v = red[0][t] + red[1][t];
        p2[((long)b * 4 + msub) * 512 + n0 + t] = v;
    }
}

// ---- kernel 5: ymean = bm + sum(yp); yvar diag = bv + sum(tp) + sum(p2) ----
__global__ void k_final(const float* __restrict__ yp, const float* __restrict__ tp,
                        const float* __restrict__ p2,
                        const float* __restrict__ bm, const float* __restrict__ bv,
                        float* __restrict__ ymean, float* __restrict__ yvar) {
    int idx = blockIdx.x * 256 + threadIdx.x;    // b*512+o
    int b = idx >> 9, o = idx & 511;
    float ym = bm[o], t1 = bv[o];
    #pragma unroll
    for (int ic = 0; ic < 8; ++ic) {
        ym += yp[((long)ic * 256 + b) * 512 + o];
        t1 += tp[((long)ic * 256 + b) * 512 + o];
    }
    long pb = (long)b * 2048 + o;
    t1 += p2[pb] + p2[pb + 512] + p2[pb + 1024] + p2[pb + 1536];
    ymean[idx] = ym;
    yvar[(long)idx * 512 + o] = t1;
}

extern "C" void kernel_launch(void* const* d_in, const int* in_sizes, int n_in,
                              void* d_out, int out_size, void* d_ws, size_t ws_size,
                              hipStream_t stream) {
    const float* x_mean = (const float*)d_in[0];
    const float* x_var  = (const float*)d_in[1];
    const float* A_mean = (const float*)d_in[2];
    const float* A_var  = (const float*)d_in[3];
    const float* b_mean = (const float*)d_in[4];
    const float* b_var  = (const float*)d_in[5];

    float* ymean = (float*)d_out;                  // [256,512]
    float* yvar  = (float*)d_out + 131072;         // [256,512,512]

    char* ws = (char*)d_ws;
    ushort* abt = (ushort*)ws;                          // 512 KB (A^T tile images)
    float*  p2  = (float*)(ws + 512 * 1024);            // [256,4,512]   2 MB
    float*  yp  = (float*)(ws + 2560 * 1024);           // [8,256,512]   4 MB
    float*  tp  = (float*)(ws + 6656 * 1024);           // [8,256,512]   4 MB
    float*  xx  = (float*)(ws + 10752 * 1024);          // [256,512]     512 KB

    k_prep_at<<<128, 256, 0, stream>>>(A_mean, abt);
    k_diag<<<512, 256, 0, stream>>>(x_var, x_mean, xx);
    k_t1<<<2048, 256, 0, stream>>>(x_mean, xx, A_mean, A_var, yp, tp);
    k_gemm2<<<4096, 256, 0, stream>>>(x_var, abt, A_mean, p2, yvar);
    k_final<<<512, 256, 0, stream>>>(yp, tp, p2, b_mean, b_var, ymean, yvar);
}